// Round 11
// baseline (908.247 us; speedup 1.0000x reference)
//
#include <hip/hip_runtime.h>

// ScaledAttention B=8,T=2048,D=1024 single-head, SCALE=1/8.
// cvt -> fused QKV proj -> causal QK^T (f16 compact tri S) -> row softmax ->
// PV. ONE unified GEMM core: 256x128 tile, BK=32, 256 thr (4 waves 2Mx2N,
// wave tile 128x64), 48KB LDS -> 3 blocks/CU (cross-block MFMA/LDS overlap,
// m97 mechanism). 64B-row swizzle: chunk ^= (row>>1)&3 (both sides).

typedef float f32x4 __attribute__((ext_vector_type(4)));
typedef _Float16 half8 __attribute__((ext_vector_type(8)));
typedef _Float16 half4 __attribute__((ext_vector_type(4)));

#define DEVINL __device__ __forceinline__
static constexpr float ATT_SCALE = 0.125f;  // 1/sqrt(1024/16)

DEVINL void gload_lds16(const _Float16* g, _Float16* l) {
  __builtin_amdgcn_global_load_lds((const __attribute__((address_space(1))) void*)g,
                                   (__attribute__((address_space(3))) void*)l, 16, 0, 0);
}

#define SBAR() __builtin_amdgcn_sched_barrier(0)

// LDS: buf b @ b*24576 bytes: A[256 rows][32 k] @0 (16KB), B[128][32] @16384
// (8KB). 64B rows = 4 16B-chunks; element (r, chunk c) at phys chunk
// c ^ ((r>>1)&3)  -> uniform 8 lanes/bank-quad for frag reads AND staging.
// Loop: RD 12 frags | lgkm0 | bar | stage(t+2)->cur, 32 MFMA | vmcnt(6) | bar.
template <int LDA, int LDB, class GA, class GB>
DEVINL void gemm_mb(GA ga, GB gb, int NT, char* ldsb, int tid, f32x4 acc[8][4]) {
  const int l = tid & 63, w = tid >> 6;
  const int wm = w >> 1, wn = w & 1;
  const int lr = l & 15, lk = l >> 4;
  // staging source maps (dst chunk = i*256 + tid, linear)
  int arow[4], acol[4], brow[2], bcol[2];
#pragma unroll
  for (int i = 0; i < 4; ++i) {
    const int P = i * 256 + tid;
    arow[i] = P >> 2;
    acol[i] = (P & 3) ^ ((arow[i] >> 1) & 3);
  }
#pragma unroll
  for (int i = 0; i < 2; ++i) {
    const int P = i * 256 + tid;
    brow[i] = P >> 2;
    bcol[i] = (P & 3) ^ ((brow[i] >> 1) & 3);
  }
  // fragment read byte offsets (swizzled)
  int aoff[8], boff[4];
#pragma unroll
  for (int i = 0; i < 8; ++i) {
    const int r = wm * 128 + i * 16 + lr;
    aoff[i] = r * 64 + ((lk ^ ((r >> 1) & 3)) << 4);
  }
#pragma unroll
  for (int j = 0; j < 4; ++j) {
    const int r = wn * 64 + j * 16 + lr;
    boff[j] = 16384 + r * 64 + ((lk ^ ((r >> 1) & 3)) << 4);
  }
  auto STG = [&](int t, int bufoff) {
    const _Float16* gA = ga(t);
#pragma unroll
    for (int i = 0; i < 4; ++i)
      gload_lds16(gA + (size_t)arow[i] * LDA + acol[i] * 8,
                  (_Float16*)(ldsb + bufoff + i * 4096 + w * 1024));
    const _Float16* gB = gb(t);
#pragma unroll
    for (int i = 0; i < 2; ++i)
      gload_lds16(gB + (size_t)brow[i] * LDB + bcol[i] * 8,
                  (_Float16*)(ldsb + bufoff + 16384 + i * 4096 + w * 1024));
  };

  STG(0, 0);
  STG(1, 24576);
  asm volatile("s_waitcnt vmcnt(6)" ::: "memory");
  __builtin_amdgcn_s_barrier();

  half8 a[8], b[4];
  for (int t = 0; t < NT; ++t) {
    const int bufoff = (t & 1) * 24576;
    const char* bb = ldsb + bufoff;
#pragma unroll
    for (int i = 0; i < 8; ++i) a[i] = *(const half8*)(bb + aoff[i]);
#pragma unroll
    for (int j = 0; j < 4; ++j) b[j] = *(const half8*)(bb + boff[j]);
    asm volatile("s_waitcnt lgkmcnt(0)" ::: "memory");
    SBAR();
    __builtin_amdgcn_s_barrier();   // all waves done reading this buf
    if (t + 2 < NT) STG(t + 2, bufoff);  // overwrite freed buf; flies under MFMA
    __builtin_amdgcn_s_setprio(1);
#pragma unroll
    for (int i = 0; i < 8; ++i)
#pragma unroll
      for (int j = 0; j < 4; ++j)
        acc[i][j] = __builtin_amdgcn_mfma_f32_16x16x32_f16(a[i], b[j], acc[i][j], 0, 0, 0);
    __builtin_amdgcn_s_setprio(0);
    if (t + 2 < NT) { asm volatile("s_waitcnt vmcnt(6)" ::: "memory"); }
    else            { asm volatile("s_waitcnt vmcnt(0)" ::: "memory"); }
    SBAR();
    __builtin_amdgcn_s_barrier();   // next tile resident for all
  }
}

// ---------------------------------------------------------------------------
__global__ __launch_bounds__(256) void cvt_all(const float* __restrict__ x,
                                               const float* __restrict__ wq,
                                               const float* __restrict__ wk,
                                               const float* __restrict__ wv,
                                               _Float16* __restrict__ xh,
                                               _Float16* __restrict__ wqh,
                                               _Float16* __restrict__ wkh,
                                               _Float16* __restrict__ wvh) {
  const int n8 = 2490368;
  for (int i = blockIdx.x * 256 + threadIdx.x; i < n8; i += 2048 * 256) {
    const float* src; _Float16* dst; int off;
    if (i < 2097152)      { src = x;  dst = xh;  off = i; }
    else if (i < 2228224) { src = wq; dst = wqh; off = i - 2097152; }
    else if (i < 2359296) { src = wk; dst = wkh; off = i - 2228224; }
    else                  { src = wv; dst = wvh; off = i - 2359296; }
    const float4* p = (const float4*)src + (size_t)off * 2;
    float4 v0 = p[0], v1 = p[1];
    half8 h;
    h[0] = (_Float16)v0.x; h[1] = (_Float16)v0.y; h[2] = (_Float16)v0.z; h[3] = (_Float16)v0.w;
    h[4] = (_Float16)v1.x; h[5] = (_Float16)v1.y; h[6] = (_Float16)v1.z; h[7] = (_Float16)v1.w;
    *((half8*)dst + off) = h;
  }
}

// Fused QKV: C[m,n]=sum_k x[m,k]W[n,k]+b[n], M=16384, N=3072, K=1024.
// 1536 jobs of 256(m) x 128(n). Epilogue through 32KB LDS halves.
__global__ __launch_bounds__(256, 3) void gemm_qkv(
    const _Float16* __restrict__ xh, const _Float16* __restrict__ Wqh,
    const _Float16* __restrict__ Wkh, const _Float16* __restrict__ Wvh,
    const float* __restrict__ bq, const float* __restrict__ bk,
    const float* __restrict__ bv, _Float16* __restrict__ Qh,
    _Float16* __restrict__ Kh, _Float16* __restrict__ VT) {
  __shared__ _Float16 lds[24576];  // 48KB
  const int tid = threadIdx.x;
  const int bid = blockIdx.x;
  const int swz = (bid & 7) * 192 + (bid >> 3);  // XCD swizzle, 1536%8==0
  const int mt = swz / 24, nt = swz % 24;
  const int sel = nt >> 3;
  const _Float16* Wsel = sel == 0 ? Wqh : (sel == 1 ? Wkh : Wvh);
  const float* bsel = sel == 0 ? bq : (sel == 1 ? bk : bv);
  const int n0 = (nt & 7) * 128;
  const _Float16* Ab = xh + (size_t)mt * 256 * 1024;
  const _Float16* Bb = Wsel + (size_t)n0 * 1024;
  f32x4 acc[8][4] = {};
  auto ga = [&](int t) { return Ab + t * 32; };
  auto gb = [&](int t) { return Bb + t * 32; };
  gemm_mb<1024, 1024>(ga, gb, 32, (char*)lds, tid, acc);
  const int l = tid & 63, w = tid >> 6;
  const int wm = w >> 1, wn = w & 1;
  const int lr = l & 15, lk = l >> 4;
  __syncthreads();
  if (sel < 2) {
    _Float16* Out = sel == 0 ? Qh : Kh;
#pragma unroll
    for (int h = 0; h < 2; ++h) {
      if (wm == h) {
#pragma unroll
        for (int ai = 0; ai < 8; ++ai) {
#pragma unroll
          for (int j = 0; j < 4; ++j) {
            const int col = wn * 64 + j * 16 + lr;
            const float bvv = bsel[n0 + col];
#pragma unroll
            for (int r = 0; r < 4; ++r) {
              const int rl = ai * 16 + lk * 4 + r;
              lds[rl * 128 + ((col + (rl >> 2) * 8) & 127)] =
                  (_Float16)(acc[ai][j][r] + bvv);
            }
          }
        }
      }
      __syncthreads();
#pragma unroll
      for (int i = 0; i < 8; ++i) {
        const int c = i * 256 + tid;
        const int rl = c >> 4, c8 = c & 15;
        half8 v = *(const half8*)&lds[rl * 128 + ((c8 * 8 + (rl >> 2) * 8) & 127)];
        *(half8*)&Out[(size_t)(mt * 256 + h * 128 + rl) * 1024 + n0 + c8 * 8] = v;
      }
      __syncthreads();
    }
  } else {
    const int bb = mt >> 3, t0 = (mt & 7) * 256;
#pragma unroll
    for (int h = 0; h < 2; ++h) {
      if (wn == h) {
#pragma unroll
        for (int ai = 0; ai < 8; ++ai) {
#pragma unroll
          for (int j = 0; j < 4; ++j) {
            const int cl = j * 16 + lr;  // local d (0..63)
            const float bvv = bsel[n0 + h * 64 + cl];
#pragma unroll
            for (int r = 0; r < 4; ++r) {
              const int row = wm * 128 + ai * 16 + lk * 4 + r;  // t (0..255)
              lds[cl * 256 + ((row + (cl >> 2) * 8) & 255)] =
                  (_Float16)(acc[ai][j][r] + bvv);
            }
          }
        }
      }
      __syncthreads();
#pragma unroll
      for (int i = 0; i < 8; ++i) {
        const int c = i * 256 + tid;
        const int d = c >> 5, t8 = c & 31;
        half8 v = *(const half8*)&lds[d * 256 + ((t8 * 8 + (d >> 2) * 8) & 255)];
        *(half8*)&VT[((size_t)bb * 1024 + n0 + h * 64 + d) * 2048 + t0 + t8 * 8] = v;
      }
      __syncthreads();
    }
  }
}

// Causal QK^T: 576 uniform 256(q) x 128(k) jobs -> f16 compact tri S
// [b][tri36][256][256] (half-tile per job), scaled, -inf above diagonal.
__global__ __launch_bounds__(256, 3) void gemm_qk(const _Float16* __restrict__ Qh,
                                                  const _Float16* __restrict__ Kh,
                                                  _Float16* __restrict__ Sc) {
  __shared__ _Float16 lds[24576];
  const int tid = threadIdx.x;
  const int j = blockIdx.x;
  const int b = j / 72, r = j % 72;
  int qt = 0, cum = 0;
  while (cum + (qt + 1) * 2 <= r) { cum += (qt + 1) * 2; ++qt; }
  const int jn = r - cum;
  const _Float16* Ab = Qh + ((size_t)b * 2048 + qt * 256) * 1024;
  const _Float16* Bb = Kh + ((size_t)b * 2048 + jn * 128) * 1024;
  f32x4 acc[8][4] = {};
  auto ga = [&](int t) { return Ab + t * 32; };
  auto gb = [&](int t) { return Bb + t * 32; };
  gemm_mb<1024, 1024>(ga, gb, 32, (char*)lds, tid, acc);
  const int l = tid & 63, w = tid >> 6;
  const int wm = w >> 1, wn = w & 1;
  const int lr = l & 15, lk = l >> 4;
  _Float16* St = Sc + ((size_t)b * 36 + (size_t)(qt * (qt + 1) / 2) + (jn >> 1)) * 65536 +
                 (jn & 1) * 128;
  const _Float16 NINF = (_Float16)(-__builtin_inff());
#pragma unroll
  for (int ai = 0; ai < 8; ++ai) {
#pragma unroll
    for (int jj = 0; jj < 4; ++jj) {
      const int col = wn * 64 + jj * 16 + lr;
      const int kg = jn * 128 + col;
#pragma unroll
      for (int rr = 0; rr < 4; ++rr) {
        const int row = wm * 128 + ai * 16 + lk * 4 + rr;
        const int qg = qt * 256 + row;
        St[(size_t)row * 256 + col] =
            (kg <= qg) ? (_Float16)(acc[ai][jj][rr] * ATT_SCALE) : NINF;
      }
    }
  }
}

// One wave per row: softmax over f16 compact S row, writes f16 P.
__global__ __launch_bounds__(256) void softmax_p(const _Float16* __restrict__ Sc,
                                                 _Float16* __restrict__ Pc) {
  const int l = threadIdx.x & 63;
  const int gid = blockIdx.x * 4 + (threadIdx.x >> 6);
  const int b = gid >> 11, q = gid & 2047;
  const int qt = q >> 8, rq = q & 255;
  const int ntile = qt + 1;
  const size_t base = ((size_t)b * 36 + (size_t)(qt * (qt + 1) / 2)) * 65536 +
                      (size_t)rq * 256 + l * 4;
  float vx[32];
  float m = -__builtin_inff();
#pragma unroll
  for (int c = 0; c < 8; ++c) {
    float x0 = -__builtin_inff(), x1 = x0, x2 = x0, x3 = x0;
    if (c < ntile) {
      half4 t = *(const half4*)&Sc[base + (size_t)c * 65536];
      x0 = (float)t[0]; x1 = (float)t[1]; x2 = (float)t[2]; x3 = (float)t[3];
    }
    vx[4 * c] = x0; vx[4 * c + 1] = x1; vx[4 * c + 2] = x2; vx[4 * c + 3] = x3;
    m = fmaxf(m, fmaxf(fmaxf(x0, x1), fmaxf(x2, x3)));
  }
#pragma unroll
  for (int s = 1; s < 64; s <<= 1) m = fmaxf(m, __shfl_xor(m, s, 64));
  float sum = 0.f;
#pragma unroll
  for (int i = 0; i < 32; ++i) { vx[i] = __expf(vx[i] - m); sum += vx[i]; }
#pragma unroll
  for (int s = 1; s < 64; s <<= 1) sum += __shfl_xor(sum, s, 64);
  const float inv = 1.f / sum;
  _Float16* Pb = Pc + base;
#pragma unroll
  for (int c = 0; c < 8; ++c) {
    if (c < ntile) {
      half4 p;
      p[0] = (_Float16)(vx[4 * c] * inv);
      p[1] = (_Float16)(vx[4 * c + 1] * inv);
      p[2] = (_Float16)(vx[4 * c + 2] * inv);
      p[3] = (_Float16)(vx[4 * c + 3] * inv);
      *(half4*)&Pb[(size_t)c * 65536] = p;
    }
  }
}

// PV: 512 jobs (qt descending = LPT), each 256(q) x 128(d) output tile.
__global__ __launch_bounds__(256, 3) void gemm_pv(const _Float16* __restrict__ Pc,
                                                  const _Float16* __restrict__ VT,
                                                  float* __restrict__ O) {
  __shared__ _Float16 lds[24576];
  const int tid = threadIdx.x;
  const int j = blockIdx.x;
  const int qt = 7 - (j >> 6);
  const int dt = (j >> 3) & 7, b = j & 7;
  const _Float16* Pb = Pc + ((size_t)b * 36 + (size_t)(qt * (qt + 1) / 2)) * 65536;
  const _Float16* Vb = VT + ((size_t)b * 1024 + dt * 128) * 2048;
  f32x4 acc[8][4] = {};
  auto ga = [&](int t) { return Pb + (size_t)(t >> 3) * 65536 + (t & 7) * 32; };
  auto gb = [&](int t) { return Vb + t * 32; };
  gemm_mb<256, 2048>(ga, gb, (qt + 1) * 8, (char*)lds, tid, acc);
  const int l = tid & 63, w = tid >> 6;
  const int wm = w >> 1, wn = w & 1;
  const int lr = l & 15, lk = l >> 4;
#pragma unroll
  for (int ai = 0; ai < 8; ++ai) {
#pragma unroll
    for (int jj = 0; jj < 4; ++jj) {
      const int cg = dt * 128 + wn * 64 + jj * 16 + lr;
#pragma unroll
      for (int rr = 0; rr < 4; ++rr) {
        const int rg = qt * 256 + wm * 128 + ai * 16 + lk * 4 + rr;
        O[((size_t)b * 2048 + rg) * 1024 + cg] = acc[ai][jj][rr];
      }
    }
  }
}

extern "C" void kernel_launch(void* const* d_in, const int* in_sizes, int n_in,
                              void* d_out, int out_size, void* d_ws, size_t ws_size,
                              hipStream_t stream) {
  const float* x    = (const float*)d_in[0];
  const float* Wq_w = (const float*)d_in[1];
  const float* Wq_b = (const float*)d_in[2];
  const float* Wk_w = (const float*)d_in[3];
  const float* Wk_b = (const float*)d_in[4];
  const float* Wv_w = (const float*)d_in[5];
  const float* Wv_b = (const float*)d_in[6];
  float* out = (float*)d_out;
  char* ws = (char*)d_ws;
  _Float16* xh  = (_Float16*)(ws);              // 32 MiB (dead after proj)
  _Float16* Wqh = (_Float16*)(ws + 33554432);
  _Float16* Wkh = (_Float16*)(ws + 35651584);
  _Float16* Wvh = (_Float16*)(ws + 37748736);
  _Float16* Sc  = (_Float16*)(ws);              // f16 compact tri S (aliases xh+W)
  _Float16* Qh  = (_Float16*)(ws + 75497472);   // 32 MiB
  _Float16* Kh  = (_Float16*)(ws + 109051904);  // 32 MiB
  _Float16* Pc  = (_Float16*)(ws + 75497472);   // f16 compact tri P (aliases Q/K)
  _Float16* VT  = (_Float16*)(ws + 142606336);  // 32 MiB

  cvt_all<<<2048, 256, 0, stream>>>(x, Wq_w, Wk_w, Wv_w, xh, Wqh, Wkh, Wvh);
  gemm_qkv<<<1536, 256, 0, stream>>>(xh, Wqh, Wkh, Wvh, Wq_b, Wk_b, Wv_b, Qh, Kh, VT);
  gemm_qk<<<576, 256, 0, stream>>>(Qh, Kh, Sc);
  softmax_p<<<4096, 256, 0, stream>>>(Sc, Pc);
  gemm_pv<<<512, 256, 0, stream>>>(Pc, VT, out);
}

// Round 13
// 429.191 us; speedup vs baseline: 2.1162x; 2.1162x over previous
//
#include <hip/hip_runtime.h>

// ScaledAttention B=8,T=2048,D=1024 single-head, SCALE=1/8.
// cvt -> QKV proj -> causal QK^T (f16 compact tri S) -> softmax (causal mask
// applied HERE) -> PV. GEMM core "absplit": 128x128 tile, 256 thr (4 waves
// 2Mx2N, acc[4][4]->AGPR), A via gload_lds ring (2x16KB, chunk^=(row&7)),
// B streamed global->regs (L2). Per K-tile: readA|lgkm0|bar1|loadB+stageA|
// vmcnt(4)|bar2|MFMA  (race-audited). 32KB LDS, ~164 regs -> 3 blocks/CU.

typedef float f32x4 __attribute__((ext_vector_type(4)));
typedef _Float16 half8 __attribute__((ext_vector_type(8)));
typedef _Float16 half4 __attribute__((ext_vector_type(4)));

#define DEVINL __device__ __forceinline__
static constexpr float ATT_SCALE = 0.125f;  // 1/sqrt(1024/16)

DEVINL void gload_lds16(const _Float16* g, _Float16* l) {
  __builtin_amdgcn_global_load_lds((const __attribute__((address_space(1))) void*)g,
                                   (__attribute__((address_space(3))) void*)l, 16, 0, 0);
}

#define SBAR() __builtin_amdgcn_sched_barrier(0)

// A tile [128 rows][64 k] f16 = 16KB/buf; element (r, 16B-chunk c) at phys
// chunk c ^ (r&7).
template <int LDA, int LDB, class GA>
DEVINL void gemm_abs(GA ga, const _Float16* __restrict__ Bb, int NT,
                     _Float16* lds, int tid, f32x4 acc[4][4]) {
  const int l = tid & 63, w = tid >> 6;
  const int wm = w >> 1, wn = w & 1;
  const int lr = l & 15, lk = l >> 4;
  int srow[4], scol[4];
#pragma unroll
  for (int i = 0; i < 4; ++i) {
    const int P = i * 256 + tid;
    srow[i] = P >> 3;
    scol[i] = (P & 7) ^ (srow[i] & 7);
  }
  int aoff[4];
#pragma unroll
  for (int i = 0; i < 4; ++i) {
    const int r = wm * 64 + i * 16 + lr;
    aoff[i] = r * 128 + ((lk ^ (r & 7)) << 4);
  }
  int bvoff[4];
#pragma unroll
  for (int j = 0; j < 4; ++j)
    bvoff[j] = (wn * 64 + j * 16 + lr) * LDB + lk * 8;

  auto STGA = [&](int t) {
    const _Float16* g0 = ga(t);
    _Float16* dst = lds + (t & 1) * 8192;
#pragma unroll
    for (int i = 0; i < 4; ++i)
      gload_lds16(g0 + (size_t)srow[i] * LDA + scol[i] * 8,
                  dst + i * 2048 + w * 512);
  };

  half8 a[4][2], b[4][2];
  STGA(0); STGA(1);
  asm volatile("s_waitcnt vmcnt(4)" ::: "memory");
  __builtin_amdgcn_s_barrier();

  for (int t = 0; t < NT; ++t) {
    const char* bufc = (const char*)(lds + (t & 1) * 8192);
#pragma unroll
    for (int i = 0; i < 4; ++i) {
      a[i][0] = *(const half8*)(bufc + aoff[i]);
      a[i][1] = *(const half8*)(bufc + (aoff[i] ^ 64));
    }
    asm volatile("s_waitcnt lgkmcnt(0)" ::: "memory");
    SBAR();
    __builtin_amdgcn_s_barrier();          // bar1: all waves done reading buf
    const _Float16* gB = Bb + t * 64;
#pragma unroll
    for (int j = 0; j < 4; ++j) {
      b[j][0] = *(const half8*)(gB + bvoff[j]);
      b[j][1] = *(const half8*)(gB + bvoff[j] + 32);
    }
    if (t + 2 < NT) {
      STGA(t + 2);  // overwrites freed buf (all reads drained before bar1)
      asm volatile("s_waitcnt vmcnt(4)" ::: "memory");  // drains A(t+1)+B(t)
    } else {
      asm volatile("s_waitcnt vmcnt(0)" ::: "memory");
    }
    SBAR();
    __builtin_amdgcn_s_barrier();          // bar2: A(t+1) landed for ALL waves
    __builtin_amdgcn_s_setprio(1);
#pragma unroll
    for (int kk = 0; kk < 2; ++kk)
#pragma unroll
      for (int i = 0; i < 4; ++i)
#pragma unroll
        for (int j = 0; j < 4; ++j)
          acc[i][j] = __builtin_amdgcn_mfma_f32_16x16x32_f16(a[i][kk], b[j][kk], acc[i][j], 0, 0, 0);
    __builtin_amdgcn_s_setprio(0);
    SBAR();
  }
}

// ---------------------------------------------------------------------------
__global__ __launch_bounds__(256) void cvt_all(const float* __restrict__ x,
                                               const float* __restrict__ wq,
                                               const float* __restrict__ wk,
                                               const float* __restrict__ wv,
                                               _Float16* __restrict__ xh,
                                               _Float16* __restrict__ wqh,
                                               _Float16* __restrict__ wkh,
                                               _Float16* __restrict__ wvh) {
  const int n8 = 2490368;
  for (int i = blockIdx.x * 256 + threadIdx.x; i < n8; i += 2048 * 256) {
    const float* src; _Float16* dst; int off;
    if (i < 2097152)      { src = x;  dst = xh;  off = i; }
    else if (i < 2228224) { src = wq; dst = wqh; off = i - 2097152; }
    else if (i < 2359296) { src = wk; dst = wkh; off = i - 2228224; }
    else                  { src = wv; dst = wvh; off = i - 2359296; }
    const float4* p = (const float4*)src + (size_t)off * 2;
    float4 v0 = p[0], v1 = p[1];
    half8 h;
    h[0] = (_Float16)v0.x; h[1] = (_Float16)v0.y; h[2] = (_Float16)v0.z; h[3] = (_Float16)v0.w;
    h[4] = (_Float16)v1.x; h[5] = (_Float16)v1.y; h[6] = (_Float16)v1.z; h[7] = (_Float16)v1.w;
    *((half8*)dst + off) = h;
  }
}

// Fused QKV: C[m,n]=sum_k x[m,k]W[n,k]+b[n]. 3072 jobs of 128x128.
__global__ __launch_bounds__(256, 3) void gemm_qkv(
    const _Float16* __restrict__ xh, const _Float16* __restrict__ Wqh,
    const _Float16* __restrict__ Wkh, const _Float16* __restrict__ Wvh,
    const float* __restrict__ bq, const float* __restrict__ bk,
    const float* __restrict__ bv, _Float16* __restrict__ Qh,
    _Float16* __restrict__ Kh, _Float16* __restrict__ VT) {
  __shared__ _Float16 lds[16384];  // 32KB: 2 A-bufs; reused by epilogue
  const int tid = threadIdx.x;
  const int bid = blockIdx.x;
  const int swz = (bid & 7) * 384 + (bid >> 3);  // XCD swizzle, 3072%8==0
  const int mt = swz / 24, nt = swz % 24;
  const int sel = nt >> 3;
  const _Float16* Wsel = sel == 0 ? Wqh : (sel == 1 ? Wkh : Wvh);
  const float* bsel = sel == 0 ? bq : (sel == 1 ? bk : bv);
  const int n0 = (nt & 7) * 128;
  const _Float16* Ab = xh + (size_t)mt * 128 * 1024;
  const _Float16* Bb = Wsel + (size_t)n0 * 1024;
  f32x4 acc[4][4] = {};
  auto ga = [&](int t) { return Ab + t * 64; };
  gemm_abs<1024, 1024>(ga, Bb, 16, lds, tid, acc);
  const int l = tid & 63, w = tid >> 6;
  const int wm = w >> 1, wn = w & 1;
  const int lr = l & 15, lk = l >> 4;
  __syncthreads();
#pragma unroll
  for (int i = 0; i < 4; ++i) {
#pragma unroll
    for (int j = 0; j < 4; ++j) {
      const int col = wn * 64 + j * 16 + lr;
      const float bvv = bsel[n0 + col];
#pragma unroll
      for (int r = 0; r < 4; ++r) {
        const int row = wm * 64 + i * 16 + lk * 4 + r;
        const float v = acc[i][j][r] + bvv;
        if (sel < 2)
          lds[row * 128 + ((col + (row >> 2) * 8) & 127)] = (_Float16)v;
        else  // transposed: [d=col][t=row]
          lds[col * 128 + ((row + (col >> 2) * 8) & 127)] = (_Float16)v;
      }
    }
  }
  __syncthreads();
#pragma unroll
  for (int i = 0; i < 8; ++i) {
    const int c = i * 256 + tid;
    const int row = c >> 4, c8 = c & 15;
    half8 v = *(const half8*)&lds[row * 128 + ((c8 * 8 + (row >> 2) * 8) & 127)];
    if (sel < 2) {
      _Float16* Out = sel == 0 ? Qh : Kh;
      *(half8*)&Out[(size_t)(mt * 128 + row) * 1024 + n0 + c8 * 8] = v;
    } else {
      const int bb = mt >> 4, t0 = (mt & 15) * 128;
      *(half8*)&VT[((size_t)bb * 1024 + n0 + row) * 2048 + t0 + c8 * 8] = v;
    }
  }
}

// Causal QK^T: 1088 jobs (b, qt2, jn2<=qt2) of 128x128 -> f16 compact tri S
// [b][tri36(256-tiles)][256][256]. Raw scaled scores; causal mask is applied
// in softmax (upper-right sub-tile of diagonal 256-tiles is never written).
__global__ __launch_bounds__(256, 3) void gemm_qk(const _Float16* __restrict__ Qh,
                                                  const _Float16* __restrict__ Kh,
                                                  _Float16* __restrict__ Sc) {
  __shared__ _Float16 lds[16384];
  const int tid = threadIdx.x;
  const int bid = blockIdx.x;
  const int b = bid / 136, r = bid % 136;
  int qt2 = 0, cum = 0;
  while (cum + qt2 + 1 <= r) { cum += qt2 + 1; ++qt2; }
  const int jn2 = r - cum;  // 0..qt2
  const _Float16* Ab = Qh + ((size_t)b * 2048 + qt2 * 128) * 1024;
  const _Float16* Bb = Kh + ((size_t)b * 2048 + jn2 * 128) * 1024;
  f32x4 acc[4][4] = {};
  auto ga = [&](int t) { return Ab + t * 64; };
  gemm_abs<1024, 1024>(ga, Bb, 16, lds, tid, acc);
  const int l = tid & 63, w = tid >> 6;
  const int wm = w >> 1, wn = w & 1;
  const int lr = l & 15, lk = l >> 4;
  const int qt = qt2 >> 1;
  _Float16* St = Sc + ((size_t)b * 36 + (size_t)(qt * (qt + 1) / 2) + (jn2 >> 1)) * 65536 +
                 (qt2 & 1) * 32768 + (jn2 & 1) * 128;
#pragma unroll
  for (int i = 0; i < 4; ++i) {
#pragma unroll
    for (int jj = 0; jj < 4; ++jj) {
      const int col = wn * 64 + jj * 16 + lr;
#pragma unroll
      for (int rr = 0; rr < 4; ++rr) {
        const int row = wm * 64 + i * 16 + lk * 4 + rr;
        St[(size_t)row * 256 + col] = (_Float16)(acc[i][jj][rr] * ATT_SCALE);
      }
    }
  }
}

// One wave per row: softmax over f16 compact S row; applies causal mask
// k<=q itself (S above diagonal may be garbage). Writes f16 P (0 masked).
__global__ __launch_bounds__(256) void softmax_p(const _Float16* __restrict__ Sc,
                                                 _Float16* __restrict__ Pc) {
  const int l = threadIdx.x & 63;
  const int gid = blockIdx.x * 4 + (threadIdx.x >> 6);
  const int b = gid >> 11, q = gid & 2047;
  const int qt = q >> 8, rq = q & 255;
  const int ntile = qt + 1;
  const size_t base = ((size_t)b * 36 + (size_t)(qt * (qt + 1) / 2)) * 65536 +
                      (size_t)rq * 256 + l * 4;
  float vx[32];
  float m = -__builtin_inff();
#pragma unroll
  for (int c = 0; c < 8; ++c) {
    const int k0 = c * 256 + l * 4;  // global k of element 0
    float x0 = -__builtin_inff(), x1 = x0, x2 = x0, x3 = x0;
    if (c < ntile) {
      half4 t = *(const half4*)&Sc[base + (size_t)c * 65536];
      x0 = (k0 <= q)     ? (float)t[0] : -__builtin_inff();
      x1 = (k0 + 1 <= q) ? (float)t[1] : -__builtin_inff();
      x2 = (k0 + 2 <= q) ? (float)t[2] : -__builtin_inff();
      x3 = (k0 + 3 <= q) ? (float)t[3] : -__builtin_inff();
    }
    vx[4 * c] = x0; vx[4 * c + 1] = x1; vx[4 * c + 2] = x2; vx[4 * c + 3] = x3;
    m = fmaxf(m, fmaxf(fmaxf(x0, x1), fmaxf(x2, x3)));
  }
#pragma unroll
  for (int s = 1; s < 64; s <<= 1) m = fmaxf(m, __shfl_xor(m, s, 64));
  float sum = 0.f;
#pragma unroll
  for (int i = 0; i < 32; ++i) { vx[i] = __expf(vx[i] - m); sum += vx[i]; }
#pragma unroll
  for (int s = 1; s < 64; s <<= 1) sum += __shfl_xor(sum, s, 64);
  const float inv = 1.f / sum;
  _Float16* Pb = Pc + base;
#pragma unroll
  for (int c = 0; c < 8; ++c) {
    if (c < ntile) {
      half4 p;
      p[0] = (_Float16)(vx[4 * c] * inv);
      p[1] = (_Float16)(vx[4 * c + 1] * inv);
      p[2] = (_Float16)(vx[4 * c + 2] * inv);
      p[3] = (_Float16)(vx[4 * c + 3] * inv);
      *(half4*)&Pb[(size_t)c * 65536] = p;
    }
  }
}

// PV: 1024 jobs (qt2 descending = LPT), each 128(q) x 128(d); NT=(qt2+1)*2.
__global__ __launch_bounds__(256, 3) void gemm_pv(const _Float16* __restrict__ Pc,
                                                  const _Float16* __restrict__ VT,
                                                  float* __restrict__ O) {
  __shared__ _Float16 lds[16384];
  const int tid = threadIdx.x;
  const int bid = blockIdx.x;
  const int qt2 = 15 - (bid >> 6);
  const int dt = (bid >> 3) & 7, b = bid & 7;
  const int qt = qt2 >> 1;
  const size_t triB = (size_t)b * 36 + (size_t)(qt * (qt + 1) / 2);
  const _Float16* Vb = VT + ((size_t)b * 1024 + dt * 128) * 2048;
  f32x4 acc[4][4] = {};
  auto ga = [&](int t) {
    return Pc + (triB + (t >> 2)) * 65536 + (qt2 & 1) * 32768 + (t & 3) * 64;
  };
  gemm_abs<256, 2048>(ga, Vb, (qt2 + 1) * 2, lds, tid, acc);
  const int l = tid & 63, w = tid >> 6;
  const int wm = w >> 1, wn = w & 1;
  const int lr = l & 15, lk = l >> 4;
#pragma unroll
  for (int i = 0; i < 4; ++i) {
#pragma unroll
    for (int jj = 0; jj < 4; ++jj) {
      const int cg = dt * 128 + wn * 64 + jj * 16 + lr;
#pragma unroll
      for (int rr = 0; rr < 4; ++rr) {
        const int rg = qt2 * 128 + wm * 64 + i * 16 + lk * 4 + rr;
        O[((size_t)b * 2048 + rg) * 1024 + cg] = acc[i][jj][rr];
      }
    }
  }
}

extern "C" void kernel_launch(void* const* d_in, const int* in_sizes, int n_in,
                              void* d_out, int out_size, void* d_ws, size_t ws_size,
                              hipStream_t stream) {
  const float* x    = (const float*)d_in[0];
  const float* Wq_w = (const float*)d_in[1];
  const float* Wq_b = (const float*)d_in[2];
  const float* Wk_w = (const float*)d_in[3];
  const float* Wk_b = (const float*)d_in[4];
  const float* Wv_w = (const float*)d_in[5];
  const float* Wv_b = (const float*)d_in[6];
  float* out = (float*)d_out;
  char* ws = (char*)d_ws;
  _Float16* xh  = (_Float16*)(ws);              // 32 MiB (dead after proj)
  _Float16* Wqh = (_Float16*)(ws + 33554432);
  _Float16* Wkh = (_Float16*)(ws + 35651584);
  _Float16* Wvh = (_Float16*)(ws + 37748736);
  _Float16* Sc  = (_Float16*)(ws);              // f16 compact tri S (aliases xh+W)
  _Float16* Qh  = (_Float16*)(ws + 75497472);   // 32 MiB
  _Float16* Kh  = (_Float16*)(ws + 109051904);  // 32 MiB
  _Float16* Pc  = (_Float16*)(ws + 75497472);   // f16 compact tri P (aliases Q/K)
  _Float16* VT  = (_Float16*)(ws + 142606336);  // 32 MiB

  cvt_all<<<2048, 256, 0, stream>>>(x, Wq_w, Wk_w, Wv_w, xh, Wqh, Wkh, Wvh);
  gemm_qkv<<<3072, 256, 0, stream>>>(xh, Wqh, Wkh, Wvh, Wq_b, Wk_b, Wv_b, Qh, Kh, VT);
  gemm_qk<<<1088, 256, 0, stream>>>(Qh, Kh, Sc);
  softmax_p<<<4096, 256, 0, stream>>>(Sc, Pc);
  gemm_pv<<<1024, 256, 0, stream>>>(Pc, VT, out);
}

// Round 14
// 265.990 us; speedup vs baseline: 3.4146x; 1.6136x over previous
//
#include <hip/hip_runtime.h>

// ScaledAttention B=8,T=2048,D=1024 single-head, SCALE=1/8.
// cvt -> QKV proj -> causal QK^T (raw f16 S) -> softmax (applies causal mask)
// -> PV. Unified m97-style core: 128x128 tile, 256 thr (4 waves 2Mx2N,
// acc[4][4]->AGPR), A AND B staged via global_load_lds into ONE 32KB buffer,
// 2-barrier full-drain loop, chunk^=(row&7) swizzle both sides.
// ~150 combined regs + 32KB LDS -> 3 blocks/CU (m97's TLP regime).

typedef float f32x4 __attribute__((ext_vector_type(4)));
typedef _Float16 half8 __attribute__((ext_vector_type(8)));
typedef _Float16 half4 __attribute__((ext_vector_type(4)));

#define DEVINL __device__ __forceinline__
static constexpr float ATT_SCALE = 0.125f;  // 1/sqrt(1024/16)

DEVINL void gload_lds16(const _Float16* g, _Float16* l) {
  __builtin_amdgcn_global_load_lds((const __attribute__((address_space(1))) void*)g,
                                   (__attribute__((address_space(3))) void*)l, 16, 0, 0);
}

#define SBAR() __builtin_amdgcn_sched_barrier(0)

// LDS (f16 units): A[128 rows][64 k] @0 (16KB), B[128][64] @8192 (16KB).
// Element (r, 16B-chunk c) at phys chunk c ^ (r&7); rows are 128B = 8 chunks.
// Loop: read 16 frags | lgkm0 | bar1 | stage(t+1) | vmcnt(0) | bar2 | 32 MFMA.
template <int LDA, int LDB, class GA, class GB>
DEVINL void core128(GA ga, GB gb, int NT, _Float16* lds, int tid, f32x4 acc[4][4]) {
  const int l = tid & 63, w = tid >> 6;
  const int wm = w >> 1, wn = w & 1;
  const int lr = l & 15, lk = l >> 4;
  int srow[4], scol[4];
#pragma unroll
  for (int i = 0; i < 4; ++i) {
    const int P = i * 256 + tid;
    srow[i] = P >> 3;
    scol[i] = (P & 7) ^ (srow[i] & 7);
  }
  int aoff[4], boff[4];
#pragma unroll
  for (int i = 0; i < 4; ++i) {
    const int ra = wm * 64 + i * 16 + lr;
    aoff[i] = ra * 128 + ((lk ^ (ra & 7)) << 4);
    const int rb = wn * 64 + i * 16 + lr;
    boff[i] = 16384 + rb * 128 + ((lk ^ (rb & 7)) << 4);
  }
  auto STG = [&](int t) {
    const _Float16* gA = ga(t);
    const _Float16* gB = gb(t);
#pragma unroll
    for (int i = 0; i < 4; ++i)
      gload_lds16(gA + (size_t)srow[i] * LDA + scol[i] * 8,
                  lds + i * 2048 + w * 512);
#pragma unroll
    for (int i = 0; i < 4; ++i)
      gload_lds16(gB + (size_t)srow[i] * LDB + scol[i] * 8,
                  lds + 8192 + i * 2048 + w * 512);
  };

  half8 a[4][2], b[4][2];
  STG(0);
  asm volatile("s_waitcnt vmcnt(0)" ::: "memory");
  __builtin_amdgcn_s_barrier();

  for (int t = 0; t < NT; ++t) {
    const char* L = (const char*)lds;
#pragma unroll
    for (int i = 0; i < 4; ++i) {
      a[i][0] = *(const half8*)(L + aoff[i]);
      a[i][1] = *(const half8*)(L + (aoff[i] ^ 64));
      b[i][0] = *(const half8*)(L + boff[i]);
      b[i][1] = *(const half8*)(L + (boff[i] ^ 64));
    }
    asm volatile("s_waitcnt lgkmcnt(0)" ::: "memory");
    SBAR();
    __builtin_amdgcn_s_barrier();      // bar1: all waves done reading buffer
    if (t + 1 < NT) STG(t + 1);        // overwrite buffer
    asm volatile("s_waitcnt vmcnt(0)" ::: "memory");
    SBAR();
    __builtin_amdgcn_s_barrier();      // bar2: next tile resident for all
    __builtin_amdgcn_s_setprio(1);
#pragma unroll
    for (int kk = 0; kk < 2; ++kk)
#pragma unroll
      for (int i = 0; i < 4; ++i)
#pragma unroll
        for (int j = 0; j < 4; ++j)
          acc[i][j] = __builtin_amdgcn_mfma_f32_16x16x32_f16(a[i][kk], b[j][kk], acc[i][j], 0, 0, 0);
    __builtin_amdgcn_s_setprio(0);
    SBAR();
  }
}

// ---------------------------------------------------------------------------
__global__ __launch_bounds__(256) void cvt_all(const float* __restrict__ x,
                                               const float* __restrict__ wq,
                                               const float* __restrict__ wk,
                                               const float* __restrict__ wv,
                                               _Float16* __restrict__ xh,
                                               _Float16* __restrict__ wqh,
                                               _Float16* __restrict__ wkh,
                                               _Float16* __restrict__ wvh) {
  const int n8 = 2490368;
  for (int i = blockIdx.x * 256 + threadIdx.x; i < n8; i += 2048 * 256) {
    const float* src; _Float16* dst; int off;
    if (i < 2097152)      { src = x;  dst = xh;  off = i; }
    else if (i < 2228224) { src = wq; dst = wqh; off = i - 2097152; }
    else if (i < 2359296) { src = wk; dst = wkh; off = i - 2228224; }
    else                  { src = wv; dst = wvh; off = i - 2359296; }
    const float4* p = (const float4*)src + (size_t)off * 2;
    float4 v0 = p[0], v1 = p[1];
    half8 h;
    h[0] = (_Float16)v0.x; h[1] = (_Float16)v0.y; h[2] = (_Float16)v0.z; h[3] = (_Float16)v0.w;
    h[4] = (_Float16)v1.x; h[5] = (_Float16)v1.y; h[6] = (_Float16)v1.z; h[7] = (_Float16)v1.w;
    *((half8*)dst + off) = h;
  }
}

// Fused QKV: C[m,n]=sum_k x[m,k]W[n,k]+b[n]. 3072 jobs of 128x128 (4.0 rounds).
__global__ __launch_bounds__(256, 3) void gemm_qkv(
    const _Float16* __restrict__ xh, const _Float16* __restrict__ Wqh,
    const _Float16* __restrict__ Wkh, const _Float16* __restrict__ Wvh,
    const float* __restrict__ bq, const float* __restrict__ bk,
    const float* __restrict__ bv, _Float16* __restrict__ Qh,
    _Float16* __restrict__ Kh, _Float16* __restrict__ VT) {
  __shared__ _Float16 lds[16384];  // 32KB: A+B staging; reused by epilogue
  const int tid = threadIdx.x;
  const int bid = blockIdx.x;
  const int swz = (bid & 7) * 384 + (bid >> 3);  // XCD swizzle, 3072%8==0
  const int mt = swz / 24, nt = swz % 24;
  const int sel = nt >> 3;
  const _Float16* Wsel = sel == 0 ? Wqh : (sel == 1 ? Wkh : Wvh);
  const float* bsel = sel == 0 ? bq : (sel == 1 ? bk : bv);
  const int n0 = (nt & 7) * 128;
  const _Float16* Ab = xh + (size_t)mt * 128 * 1024;
  const _Float16* Bb = Wsel + (size_t)n0 * 1024;
  f32x4 acc[4][4] = {};
  auto ga = [&](int t) { return Ab + t * 64; };
  auto gb = [&](int t) { return Bb + t * 64; };
  core128<1024, 1024>(ga, gb, 16, lds, tid, acc);
  const int l = tid & 63, w = tid >> 6;
  const int wm = w >> 1, wn = w & 1;
  const int lr = l & 15, lk = l >> 4;
  __syncthreads();
#pragma unroll
  for (int i = 0; i < 4; ++i) {
#pragma unroll
    for (int j = 0; j < 4; ++j) {
      const int col = wn * 64 + j * 16 + lr;
      const float bvv = bsel[n0 + col];
#pragma unroll
      for (int r = 0; r < 4; ++r) {
        const int row = wm * 64 + i * 16 + lk * 4 + r;
        const float v = acc[i][j][r] + bvv;
        if (sel < 2)
          lds[row * 128 + ((col + (row >> 2) * 8) & 127)] = (_Float16)v;
        else  // transposed: [d=col][t=row]
          lds[col * 128 + ((row + (col >> 2) * 8) & 127)] = (_Float16)v;
      }
    }
  }
  __syncthreads();
#pragma unroll
  for (int i = 0; i < 8; ++i) {
    const int c = i * 256 + tid;
    const int row = c >> 4, c8 = c & 15;
    half8 v = *(const half8*)&lds[row * 128 + ((c8 * 8 + (row >> 2) * 8) & 127)];
    if (sel < 2) {
      _Float16* Out = sel == 0 ? Qh : Kh;
      *(half8*)&Out[(size_t)(mt * 128 + row) * 1024 + n0 + c8 * 8] = v;
    } else {
      const int bb = mt >> 4, t0 = (mt & 15) * 128;
      *(half8*)&VT[((size_t)bb * 1024 + n0 + row) * 2048 + t0 + c8 * 8] = v;
    }
  }
}

// Causal QK^T: 1088 jobs (b, qt2, jn2<=qt2) of 128x128 -> raw scaled f16 S in
// compact tri layout [b][tri36(256-tiles)][256][256]. Mask applied in softmax.
__global__ __launch_bounds__(256, 3) void gemm_qk(const _Float16* __restrict__ Qh,
                                                  const _Float16* __restrict__ Kh,
                                                  _Float16* __restrict__ Sc) {
  __shared__ _Float16 lds[16384];
  const int tid = threadIdx.x;
  const int bid = blockIdx.x;
  const int b = bid / 136, r = bid % 136;
  int qt2 = 0, cum = 0;
  while (cum + qt2 + 1 <= r) { cum += qt2 + 1; ++qt2; }
  const int jn2 = r - cum;  // 0..qt2
  const _Float16* Ab = Qh + ((size_t)b * 2048 + qt2 * 128) * 1024;
  const _Float16* Bb = Kh + ((size_t)b * 2048 + jn2 * 128) * 1024;
  f32x4 acc[4][4] = {};
  auto ga = [&](int t) { return Ab + t * 64; };
  auto gb = [&](int t) { return Bb + t * 64; };
  core128<1024, 1024>(ga, gb, 16, lds, tid, acc);
  const int l = tid & 63, w = tid >> 6;
  const int wm = w >> 1, wn = w & 1;
  const int lr = l & 15, lk = l >> 4;
  const int qt = qt2 >> 1;
  _Float16* St = Sc + ((size_t)b * 36 + (size_t)(qt * (qt + 1) / 2) + (jn2 >> 1)) * 65536 +
                 (qt2 & 1) * 32768 + (jn2 & 1) * 128;
#pragma unroll
  for (int i = 0; i < 4; ++i) {
#pragma unroll
    for (int jj = 0; jj < 4; ++jj) {
      const int col = wn * 64 + jj * 16 + lr;
#pragma unroll
      for (int rr = 0; rr < 4; ++rr) {
        const int row = wm * 64 + i * 16 + lk * 4 + rr;
        St[(size_t)row * 256 + col] = (_Float16)(acc[i][jj][rr] * ATT_SCALE);
      }
    }
  }
}

// One wave per row: softmax over f16 compact S row; applies causal mask k<=q
// (S above diagonal may be garbage). Writes f16 P (0 where masked).
__global__ __launch_bounds__(256) void softmax_p(const _Float16* __restrict__ Sc,
                                                 _Float16* __restrict__ Pc) {
  const int l = threadIdx.x & 63;
  const int gid = blockIdx.x * 4 + (threadIdx.x >> 6);
  const int b = gid >> 11, q = gid & 2047;
  const int qt = q >> 8, rq = q & 255;
  const int ntile = qt + 1;
  const size_t base = ((size_t)b * 36 + (size_t)(qt * (qt + 1) / 2)) * 65536 +
                      (size_t)rq * 256 + l * 4;
  float vx[32];
  float m = -__builtin_inff();
#pragma unroll
  for (int c = 0; c < 8; ++c) {
    const int k0 = c * 256 + l * 4;
    float x0 = -__builtin_inff(), x1 = x0, x2 = x0, x3 = x0;
    if (c < ntile) {
      half4 t = *(const half4*)&Sc[base + (size_t)c * 65536];
      x0 = (k0 <= q)     ? (float)t[0] : -__builtin_inff();
      x1 = (k0 + 1 <= q) ? (float)t[1] : -__builtin_inff();
      x2 = (k0 + 2 <= q) ? (float)t[2] : -__builtin_inff();
      x3 = (k0 + 3 <= q) ? (float)t[3] : -__builtin_inff();
    }
    vx[4 * c] = x0; vx[4 * c + 1] = x1; vx[4 * c + 2] = x2; vx[4 * c + 3] = x3;
    m = fmaxf(m, fmaxf(fmaxf(x0, x1), fmaxf(x2, x3)));
  }
#pragma unroll
  for (int s = 1; s < 64; s <<= 1) m = fmaxf(m, __shfl_xor(m, s, 64));
  float sum = 0.f;
#pragma unroll
  for (int i = 0; i < 32; ++i) { vx[i] = __expf(vx[i] - m); sum += vx[i]; }
#pragma unroll
  for (int s = 1; s < 64; s <<= 1) sum += __shfl_xor(sum, s, 64);
  const float inv = 1.f / sum;
  _Float16* Pb = Pc + base;
#pragma unroll
  for (int c = 0; c < 8; ++c) {
    if (c < ntile) {
      half4 p;
      p[0] = (_Float16)(vx[4 * c] * inv);
      p[1] = (_Float16)(vx[4 * c + 1] * inv);
      p[2] = (_Float16)(vx[4 * c + 2] * inv);
      p[3] = (_Float16)(vx[4 * c + 3] * inv);
      *(half4*)&Pb[(size_t)c * 65536] = p;
    }
  }
}

// PV: 1024 jobs (qt2 descending = LPT), each 128(q) x 128(d); NT=(qt2+1)*2.
__global__ __launch_bounds__(256, 3) void gemm_pv(const _Float16* __restrict__ Pc,
                                                  const _Float16* __restrict__ VT,
                                                  float* __restrict__ O) {
  __shared__ _Float16 lds[16384];
  const int tid = threadIdx.x;
  const int bid = blockIdx.x;
  const int qt2 = 15 - (bid >> 6);
  const int dt = (bid >> 3) & 7, b = bid & 7;
  const int qt = qt2 >> 1;
  const size_t triB = (size_t)b * 36 + (size_t)(qt * (qt + 1) / 2);
  const _Float16* Vb = VT + ((size_t)b * 1024 + dt * 128) * 2048;
  f32x4 acc[4][4] = {};
  auto ga = [&](int t) {
    return Pc + (triB + (t >> 2)) * 65536 + (qt2 & 1) * 32768 + (t & 3) * 64;
  };
  auto gb = [&](int t) { return Vb + t * 64; };
  core128<256, 2048>(ga, gb, (qt2 + 1) * 2, lds, tid, acc);
  const int l = tid & 63, w = tid >> 6;
  const int wm = w >> 1, wn = w & 1;
  const int lr = l & 15, lk = l >> 4;
#pragma unroll
  for (int i = 0; i < 4; ++i) {
#pragma unroll
    for (int jj = 0; jj < 4; ++jj) {
      const int cg = dt * 128 + wn * 64 + jj * 16 + lr;
#pragma unroll
      for (int rr = 0; rr < 4; ++rr) {
        const int rg = qt2 * 128 + wm * 64 + i * 16 + lk * 4 + rr;
        O[((size_t)b * 2048 + rg) * 1024 + cg] = acc[i][jj][rr];
      }
    }
  }
}

extern "C" void kernel_launch(void* const* d_in, const int* in_sizes, int n_in,
                              void* d_out, int out_size, void* d_ws, size_t ws_size,
                              hipStream_t stream) {
  const float* x    = (const float*)d_in[0];
  const float* Wq_w = (const float*)d_in[1];
  const float* Wq_b = (const float*)d_in[2];
  const float* Wk_w = (const float*)d_in[3];
  const float* Wk_b = (const float*)d_in[4];
  const float* Wv_w = (const float*)d_in[5];
  const float* Wv_b = (const float*)d_in[6];
  float* out = (float*)d_out;
  char* ws = (char*)d_ws;
  _Float16* xh  = (_Float16*)(ws);              // 32 MiB (dead after proj)
  _Float16* Wqh = (_Float16*)(ws + 33554432);
  _Float16* Wkh = (_Float16*)(ws + 35651584);
  _Float16* Wvh = (_Float16*)(ws + 37748736);
  _Float16* Sc  = (_Float16*)(ws);              // f16 compact tri S (aliases xh+W)
  _Float16* Qh  = (_Float16*)(ws + 75497472);   // 32 MiB
  _Float16* Kh  = (_Float16*)(ws + 109051904);  // 32 MiB
  _Float16* Pc  = (_Float16*)(ws + 75497472);   // f16 compact tri P (aliases Q/K)
  _Float16* VT  = (_Float16*)(ws + 142606336);  // 32 MiB

  cvt_all<<<2048, 256, 0, stream>>>(x, Wq_w, Wk_w, Wv_w, xh, Wqh, Wkh, Wvh);
  gemm_qkv<<<3072, 256, 0, stream>>>(xh, Wqh, Wkh, Wvh, Wq_b, Wk_b, Wv_b, Qh, Kh, VT);
  gemm_qk<<<1088, 256, 0, stream>>>(Qh, Kh, Sc);
  softmax_p<<<4096, 256, 0, stream>>>(Sc, Pc);
  gemm_pv<<<1024, 256, 0, stream>>>(Pc, VT, out);
}